// Round 10
// baseline (136.294 us; speedup 1.0000x reference)
//
#include <hip/hip_runtime.h>
#include <hip/hip_bf16.h>
#include <math.h>

typedef __bf16 bf16;
typedef __attribute__((ext_vector_type(8))) __bf16 bf16x8;
typedef __attribute__((ext_vector_type(4))) __bf16 bf16x4;
typedef __attribute__((ext_vector_type(4))) float f32x4;
typedef __attribute__((ext_vector_type(16))) float f32x16;

typedef __attribute__((address_space(1))) void* as1ptr;
typedef __attribute__((address_space(3))) void* as3ptr;

__device__ __forceinline__ void gload16(const void* g, void* lds) {
  __builtin_amdgcn_global_load_lds((as1ptr)(unsigned long long)(g),
                                   (as3ptr)(unsigned long long)(lds), 16, 0, 0);
}

#define MFMA16(a, b, c) __builtin_amdgcn_mfma_f32_16x16x32_bf16((a), (b), (c), 0, 0, 0)
#define MFMA32(a, b, c) __builtin_amdgcn_mfma_f32_32x32x16_bf16((a), (b), (c), 0, 0, 0)
#define EXP2(x) __builtin_amdgcn_exp2f(x)
#define WAITV4 asm volatile("s_waitcnt vmcnt(4)" ::: "memory")
#define WAITV0 asm volatile("s_waitcnt vmcnt(0)" ::: "memory")
#define BAR() __builtin_amdgcn_s_barrier()
#define PRIO1() __builtin_amdgcn_s_setprio(1)
#define PRIO0() __builtin_amdgcn_s_setprio(0)

#define SEQ 4096
#define EMB 768
// 1/sqrt(768) * log2(e): attention scores live in the log2 domain
#define QSC (0.036084391824351615f * 1.4426950408889634f)

// ------------- fused f32->bf16 converts (x, Wq, Wk, Wv, Wo) + mask tile-flag bits -------------
#define NCVT 2688  // 1536 (x) + 4*288 (weights)
__global__ __launch_bounds__(256)
void cvt_all_kernel(const float* __restrict__ x, const float* __restrict__ Wq,
                    const float* __restrict__ Wk, const float* __restrict__ Wv,
                    const float* __restrict__ Wo,
                    bf16* __restrict__ xb, bf16* __restrict__ Wqb, bf16* __restrict__ Wkb,
                    bf16* __restrict__ Wvb, bf16* __restrict__ Wob,
                    const unsigned char* __restrict__ mask,
                    unsigned long long* __restrict__ tf64) {
  int b = blockIdx.x;
  if (b == NCVT) {  // bit t of *tf64 = any(mask[64t .. 64t+63]), t = 0..63
    int t = threadIdx.x;
    if (t < 64) {
      unsigned v = 0;
      const unsigned char* mp = mask + t * 64;
      for (int i = 0; i < 64; i++) v |= mp[i];
      unsigned long long bits = __ballot(v != 0);
      if (t == 0) *tf64 = bits;
    }
    return;
  }
  const float* in;
  bf16* out;
  int base;
  if (b < 1536) {
    in = x; out = xb; base = b;
  } else {
    int r = b - 1536, seg = r / 288, off = r % 288;
    in  = (seg == 0) ? Wq  : (seg == 1) ? Wk  : (seg == 2) ? Wv  : Wo;
    out = (seg == 0) ? Wqb : (seg == 1) ? Wkb : (seg == 2) ? Wvb : Wob;
    base = off;
  }
  int i = (base * 256 + threadIdx.x) * 8;
  float4 a = *(const float4*)(in + i);
  float4 c = *(const float4*)(in + i + 4);
  bf16x8 v;
  v[0] = (bf16)a.x; v[1] = (bf16)a.y; v[2] = (bf16)a.z; v[3] = (bf16)a.w;
  v[4] = (bf16)c.x; v[5] = (bf16)c.y; v[6] = (bf16)c.z; v[7] = (bf16)c.w;
  *(bf16x8*)(out + i) = v;
}

// ---------------- GEMM: out[m][n] = sum_k A[m][k]*B[n][k] + bias[n] ----------------
// 3-deep LDS pipeline, counted vmcnt(4), single raw barrier per K-step.
// MODE 0: f32 row-major output (final projection).
// MODE 1: QKV. Q: scaled (1/sqrt(E)*log2e) head-major; K: byte-swizzled rows;
//         V: transposed V^T, slot-permuted (bits 2<->3 of within-16 key index) + swizzled.
template <int MODE>
__global__ __launch_bounds__(256)
void gemm_bt_kernel(const bf16* __restrict__ A,
                    const bf16* __restrict__ B0, const bf16* __restrict__ B1,
                    const bf16* __restrict__ B2,
                    const float* __restrict__ bias0, const float* __restrict__ bias1,
                    const float* __restrict__ bias2,
                    float* __restrict__ outF, bf16* __restrict__ Qh,
                    char* __restrict__ Kswz, char* __restrict__ Vswz) {
  __shared__ __attribute__((aligned(16))) char Asb[3][8192];
  __shared__ __attribute__((aligned(16))) char Bsb[3][8192];
  const int tid = threadIdx.x;
  const int wid = tid >> 6, lane = tid & 63;
  const int g = lane >> 4, c16 = lane & 15;
  const int wr = wid >> 1, wc = wid & 1;
  const int bm0 = blockIdx.x * 128;

  const bf16* Bp;
  const float* bias;
  int nb, mat = 0;
  if (MODE == 1) {
    mat = blockIdx.y / 6;
    nb = (blockIdx.y % 6) * 128;
    Bp = (mat == 0) ? B0 : (mat == 1 ? B1 : B2);
    bias = (mat == 0) ? bias0 : (mat == 1 ? bias1 : bias2);
  } else {
    nb = blockIdx.y * 128;
    Bp = B0;
    bias = bias0;
  }

  const int arow = tid >> 2, acol = (tid & 3) * 16;  // tid*16 -> (row, 16B-col) in 128x32 tile

#define STAGE_G(k, b)                                                              \
  do {                                                                             \
    gload16((const char*)A + (size_t)(bm0 + arow) * (EMB * 2) + (k)*64 + acol,     \
            &Asb[b][wid * 1024]);                                                  \
    gload16((const char*)A + (size_t)(bm0 + 64 + arow) * (EMB * 2) + (k)*64 + acol,\
            &Asb[b][4096 + wid * 1024]);                                           \
    gload16((const char*)Bp + (size_t)(nb + arow) * (EMB * 2) + (k)*64 + acol,     \
            &Bsb[b][wid * 1024]);                                                  \
    gload16((const char*)Bp + (size_t)(nb + 64 + arow) * (EMB * 2) + (k)*64 + acol,\
            &Bsb[b][4096 + wid * 1024]);                                           \
  } while (0)

  f32x4 acc[4][4];
#pragma unroll
  for (int i = 0; i < 4; i++)
#pragma unroll
    for (int j = 0; j < 4; j++) acc[i][j] = f32x4{0.f, 0.f, 0.f, 0.f};

#define COMPUTE_G(cur)                                                         \
  do {                                                                         \
    bf16x8 a[4], b[4];                                                         \
    _Pragma("unroll") for (int i = 0; i < 4; i++)                              \
        a[i] = *(const bf16x8*)(&Asb[cur][(wr * 64 + i * 16 + c16) * 64 + g * 16]); \
    _Pragma("unroll") for (int j = 0; j < 4; j++)                              \
        b[j] = *(const bf16x8*)(&Bsb[cur][(wc * 64 + j * 16 + c16) * 64 + g * 16]); \
    PRIO1();                                                                   \
    _Pragma("unroll") for (int i = 0; i < 4; i++)                              \
        _Pragma("unroll") for (int j = 0; j < 4; j++)                          \
            acc[i][j] = MFMA16(a[i], b[j], acc[i][j]);                         \
    PRIO0();                                                                   \
  } while (0)

  STAGE_G(0, 0);
  STAGE_G(1, 1);
  int cur = 0;
  for (int kk = 0; kk < EMB / 32 - 1; ++kk) {
    WAITV4;
    BAR();
    if (kk < EMB / 32 - 2) {
      int stb = (cur == 0) ? 2 : cur - 1;  // (kk+2)%3
      STAGE_G(kk + 2, stb);
    }
    COMPUTE_G(cur);
    cur = (cur == 2) ? 0 : cur + 1;
  }
  WAITV0;
  BAR();
  COMPUTE_G(cur);
#undef STAGE_G
#undef COMPUTE_G

#pragma unroll
  for (int i = 0; i < 4; i++) {
#pragma unroll
    for (int j = 0; j < 4; j++) {
      int colL = nb + wc * 64 + j * 16 + c16;
      float bval = bias[colL];
#pragma unroll
      for (int r = 0; r < 4; r++) {
        int row = bm0 + wr * 64 + i * 16 + 4 * g + r;
        float val = acc[i][j][r] + bval;
        if (MODE == 0) {
          outF[(size_t)row * EMB + colL] = val;
        } else {
          int hh = colL >> 6, d = colL & 63;
          if (mat == 0) {
            Qh[((size_t)hh * SEQ + row) * 64 + d] = (bf16)(val * QSC);
          } else if (mat == 1) {
            *(bf16*)(Kswz + ((size_t)hh * SEQ + row) * 128 +
                     ((d * 2) ^ ((row & 7) << 4))) = (bf16)val;
          } else {
            // V^T slot permutation: within each 16-key group, key w -> slot (swap bits 2,3)
            int kk2 = row & 63;
            int cc = (kk2 & 48) | (kk2 & 3) | ((kk2 & 4) << 1) | ((kk2 & 8) >> 1);
            *(bf16*)(Vswz + ((size_t)hh * 64 + d) * 8192 + (size_t)(row >> 6) * 128 +
                     ((cc * 2) ^ ((d & 7) << 4))) = (bf16)val;
          }
        }
      }
    }
  }
}

// -------- Flash attention: 32x32 MFMA, 4 waves (2qh x 2kh), A/B q-doubling --------
// Each wave: 64 queries (A: l31, B: 32+l31) x 32 keys per tile; K/V fragments read
// ONCE and reused for both q-halves (reads:MFMA = 1:2). QB=128, key-split 4 (NT=16),
// grid 1536, 2-buffer 32KB LDS. Max-free softmax (p = exp2(s), no cross-lane in loop).
__global__ __launch_bounds__(256)
void attn_kernel(const char* __restrict__ Kswz, const char* __restrict__ Vswz,
                 const bf16* __restrict__ Qh, const unsigned char* __restrict__ mask,
                 const unsigned long long* __restrict__ tf64,
                 bf16* __restrict__ P0, bf16* __restrict__ P1,
                 bf16* __restrict__ P2, bf16* __restrict__ P3, float* __restrict__ lm) {
  __shared__ __attribute__((aligned(16))) char LBUF[32768];  // 2 x (8KB K + 8KB V)
  const int tid = threadIdx.x;
  const int wid = tid >> 6, lane = tid & 63;
  const int qh = wid >> 1, kh = wid & 1;
  const int l31 = lane & 31, hi = lane >> 5;
  // XCD swizzle: 1536 blocks, contiguous 192-block work range per XCD (~1.5 heads hot).
  const int bsw = ((blockIdx.x & 7) * 192) + (blockIdx.x >> 3);
  const int h = bsw >> 7;    // 128 work units per head
  const int rem = bsw & 127;
  const int qb = rem >> 2;   // 32 query-blocks of 128
  const int ks = rem & 3;    // key quarter: keys [ks*1024, ks*1024+1024)
  const unsigned long long tfb = *tf64;
  const int NT = 16;         // 1024 / 64

  // staging sources: tid*16 covers 4KB per gload (256 threads x 16B)
  const char* ksrc = Kswz + (size_t)h * SEQ * 128 + (size_t)ks * 1024 * 128 + tid * 16;
  const char* vsrc = Vswz + ((size_t)h * 64 + (tid >> 3)) * 8192 + ks * 2048 + (tid & 7) * 16;

#define STAGE(t, b)                                                             \
  do {                                                                          \
    gload16(ksrc + (size_t)(t)*8192,        LBUF + (b)*16384 + wid * 1024);     \
    gload16(ksrc + (size_t)(t)*8192 + 4096, LBUF + (b)*16384 + 4096 + wid * 1024); \
    gload16(vsrc + (size_t)(t)*128,             LBUF + (b)*16384 + 8192 + wid * 1024); \
    gload16(vsrc + 32 * 8192 + (size_t)(t)*128, LBUF + (b)*16384 + 12288 + wid * 1024); \
  } while (0)

  STAGE(0, 0);  // issue earliest

  bf16x8 qaA[4], qaB[4];  // B-frags: Q[q = qb*128 + qh*64 + {l31, 32+l31}][d]
  {
    const bf16* qp = Qh + ((size_t)h * SEQ + qb * 128 + qh * 64 + l31) * 64 + hi * 8;
#pragma unroll
    for (int j = 0; j < 4; ++j) {
      qaA[j] = *(const bf16x8*)(qp + j * 16);
      qaB[j] = *(const bf16x8*)(qp + 32 * 64 + j * 16);
    }
  }

  f32x16 otA0, otA1, otB0, otB1;  // O^T: d = 32f + (r&3)+8*(r>>2)+4hi, q = l31 (+32 for B)
#pragma unroll
  for (int r = 0; r < 16; r++) { otA0[r] = 0.f; otA1[r] = 0.f; otB0[r] = 0.f; otB1[r] = 0.f; }
  float lA_ = 0.f, lB_ = 0.f;

  const int krow = kh * 32 + l31;          // K row this lane supplies (A-frag m)
  const int ksw = (krow & 7) << 4;
  const int vsw = (l31 & 7) << 4;          // V^T row swizzle (rows l31, 32+l31: same &7)
  const int vcb = kh * 64 + hi * 16;       // V^T slot-col byte base for this wave

#define COMPUTE(t, cur)                                                          \
  do {                                                                           \
    const char* Kb = LBUF + (cur)*16384;                                         \
    const char* Vb = Kb + 8192;                                                  \
    bf16x8 kf0 = *(const bf16x8*)(Kb + krow * 128 + ((hi * 16) ^ ksw));          \
    bf16x8 kf1 = *(const bf16x8*)(Kb + krow * 128 + ((32 + hi * 16) ^ ksw));     \
    bf16x8 kf2 = *(const bf16x8*)(Kb + krow * 128 + ((64 + hi * 16) ^ ksw));     \
    bf16x8 kf3 = *(const bf16x8*)(Kb + krow * 128 + ((96 + hi * 16) ^ ksw));     \
    f32x16 sA, sB;                                                               \
    _Pragma("unroll") for (int r = 0; r < 16; r++) { sA[r] = 0.f; sB[r] = 0.f; } \
    PRIO1();                                                                     \
    sA = MFMA32(kf0, qaA[0], sA);                                                \
    sB = MFMA32(kf0, qaB[0], sB);                                                \
    sA = MFMA32(kf1, qaA[1], sA);                                                \
    sB = MFMA32(kf1, qaB[1], sB);                                                \
    sA = MFMA32(kf2, qaA[2], sA);                                                \
    sB = MFMA32(kf2, qaB[2], sB);                                                \
    sA = MFMA32(kf3, qaA[3], sA);                                                \
    sB = MFMA32(kf3, qaB[3], sB);                                                \
    PRIO0();                                                                     \
    if (tfb & (1ull << (ks * 16 + (t)))) {                                       \
      _Pragma("unroll") for (int r = 0; r < 16; r++) {                           \
        int key = ks * 1024 + (t)*64 + kh * 32 + (r & 3) + 8 * (r >> 2) + 4 * hi;\
        if (mask[key]) { sA[r] = -INFINITY; sB[r] = -INFINITY; }                 \
      }                                                                          \
    }                                                                            \
    bf16x8 pbA0, pbA1, pbB0, pbB1;                                               \
    {                                                                            \
      _Pragma("unroll") for (int r = 0; r < 16; r++) sA[r] = EXP2(sA[r]);        \
      lA_ += (((sA[0] + sA[1]) + (sA[2] + sA[3])) + ((sA[4] + sA[5]) + (sA[6] + sA[7]))) + \
             (((sA[8] + sA[9]) + (sA[10] + sA[11])) + ((sA[12] + sA[13]) + (sA[14] + sA[15]))); \
      _Pragma("unroll") for (int e = 0; e < 8; ++e) {                            \
        pbA0[e] = (bf16)sA[e];                                                   \
        pbA1[e] = (bf16)sA[8 + e];                                               \
      }                                                                          \
    }                                                                            \
    {                                                                            \
      _Pragma("unroll") for (int r = 0; r < 16; r++) sB[r] = EXP2(sB[r]);        \
      lB_ += (((sB[0] + sB[1]) + (sB[2] + sB[3])) + ((sB[4] + sB[5]) + (sB[6] + sB[7]))) + \
             (((sB[8] + sB[9]) + (sB[10] + sB[11])) + ((sB[12] + sB[13]) + (sB[14] + sB[15]))); \
      _Pragma("unroll") for (int e = 0; e < 8; ++e) {                            \
        pbB0[e] = (bf16)sB[e];                                                   \
        pbB1[e] = (bf16)sB[8 + e];                                               \
      }                                                                          \
    }                                                                            \
    bf16x8 vf00 = *(const bf16x8*)(Vb + l31 * 128 + ((vcb) ^ vsw));              \
    bf16x8 vf01 = *(const bf16x8*)(Vb + l31 * 128 + ((vcb + 32) ^ vsw));         \
    bf16x8 vf10 = *(const bf16x8*)(Vb + (32 + l31) * 128 + ((vcb) ^ vsw));       \
    bf16x8 vf11 = *(const bf16x8*)(Vb + (32 + l31) * 128 + ((vcb + 32) ^ vsw));  \
    PRIO1();                                                                     \
    otA0 = MFMA32(vf00, pbA0, otA0);                                             \
    otB0 = MFMA32(vf00, pbB0, otB0);                                             \
    otA0 = MFMA32(vf01, pbA1, otA0);                                             \
    otB0 = MFMA32(vf01, pbB1, otB0);                                             \
    otA1 = MFMA32(vf10, pbA0, otA1);                                             \
    otB1 = MFMA32(vf10, pbB0, otB1);                                             \
    otA1 = MFMA32(vf11, pbA1, otA1);                                             \
    otB1 = MFMA32(vf11, pbB1, otB1);                                             \
    PRIO0();                                                                     \
  } while (0)

  // 2-buffer pipeline: one barrier per tile; STAGE(t+1) targets the buffer all
  // waves finished reading in iter t-1 (guaranteed by the barrier at top of t).
  for (int t = 0; t < NT; ++t) {
    WAITV0;
    BAR();
    if (t < NT - 1) STAGE(t + 1, (t + 1) & 1);
    COMPUTE(t, t & 1);
  }
#undef STAGE
#undef COMPUTE

  // combine the two hi-halves of each q-row's key coverage
  lA_ += __shfl_xor(lA_, 32);
  lB_ += __shfl_xor(lB_, 32);

  // ---- merge kh=0 / kh=1 partials (plain sums; park A then B to fit 16KB+2KB LDS) ----
  __syncthreads();
  float* ml = (float*)(LBUF + 16384);  // [4 waves][64 lanes][2]
  ml[(wid * 64 + lane) * 2 + 0] = lA_;
  ml[(wid * 64 + lane) * 2 + 1] = lB_;
  __syncthreads();
  const int pw = wid ^ 1;
  const float ltA = lA_ + ml[(pw * 64 + lane) * 2 + 0];
  const float ltB = lB_ + ml[(pw * 64 + lane) * 2 + 1];
  bf16* Op = (ks == 0) ? P0 : (ks == 1) ? P1 : (ks == 2) ? P2 : P3;
  char* pbase = LBUF + qh * 8192 + lane * 128;  // [2 qh][64 lanes][128B]
  const int osw = (lane & 7) << 4;
  const int tokA = qb * 128 + qh * 64 + l31;
  // phase A
  if (kh == 1) {
#pragma unroll
    for (int u = 0; u < 4; ++u) {
      *(f32x4*)(pbase + ((u * 16) ^ osw)) =
          f32x4{otA0[4 * u], otA0[4 * u + 1], otA0[4 * u + 2], otA0[4 * u + 3]};
      *(f32x4*)(pbase + (((4 + u) * 16) ^ osw)) =
          f32x4{otA1[4 * u], otA1[4 * u + 1], otA1[4 * u + 2], otA1[4 * u + 3]};
    }
  }
  __syncthreads();
  if (kh == 0) {
    float inv = 1.f / ltA;
    bf16* op = Op + (size_t)tokA * EMB + h * 64;
#pragma unroll
    for (int u = 0; u < 4; ++u) {
      f32x4 w0 = *(const f32x4*)(pbase + ((u * 16) ^ osw));
      f32x4 w1 = *(const f32x4*)(pbase + (((4 + u) * 16) ^ osw));
      bf16x4 o0, o1;
#pragma unroll
      for (int e = 0; e < 4; ++e) {
        o0[e] = (bf16)((otA0[4 * u + e] + w0[e]) * inv);
        o1[e] = (bf16)((otA1[4 * u + e] + w1[e]) * inv);
      }
      *(bf16x4*)(op + 8 * u + 4 * hi) = o0;        // d = 8u + 4hi + e
      *(bf16x4*)(op + 32 + 8 * u + 4 * hi) = o1;   // d = 32 + ...
    }
    if (lane < 32) lm[(((size_t)ks * 12 + h) << 12) + tokA] = ltA;
  }
  __syncthreads();
  // phase B
  if (kh == 1) {
#pragma unroll
    for (int u = 0; u < 4; ++u) {
      *(f32x4*)(pbase + ((u * 16) ^ osw)) =
          f32x4{otB0[4 * u], otB0[4 * u + 1], otB0[4 * u + 2], otB0[4 * u + 3]};
      *(f32x4*)(pbase + (((4 + u) * 16) ^ osw)) =
          f32x4{otB1[4 * u], otB1[4 * u + 1], otB1[4 * u + 2], otB1[4 * u + 3]};
    }
  }
  __syncthreads();
  if (kh == 0) {
    float inv = 1.f / ltB;
    bf16* op = Op + (size_t)(tokA + 32) * EMB + h * 64;
#pragma unroll
    for (int u = 0; u < 4; ++u) {
      f32x4 w0 = *(const f32x4*)(pbase + ((u * 16) ^ osw));
      f32x4 w1 = *(const f32x4*)(pbase + (((4 + u) * 16) ^ osw));
      bf16x4 o0, o1;
#pragma unroll
      for (int e = 0; e < 4; ++e) {
        o0[e] = (bf16)((otB0[4 * u + e] + w0[e]) * inv);
        o1[e] = (bf16)((otB1[4 * u + e] + w1[e]) * inv);
      }
      *(bf16x4*)(op + 8 * u + 4 * hi) = o0;
      *(bf16x4*)(op + 32 + 8 * u + 4 * hi) = o1;
    }
    if (lane < 32) lm[(((size_t)ks * 12 + h) << 12) + tokA + 32] = ltB;
  }
}

// ---- merge the four key-split quarters: O = sum(l_i * P_i) / sum(l_i), into P0 ----
__global__ __launch_bounds__(256)
void merge_kernel(bf16* __restrict__ P0, const bf16* __restrict__ P1,
                  const bf16* __restrict__ P2, const bf16* __restrict__ P3,
                  const float* __restrict__ lm) {
  int idx = (blockIdx.x * 256 + threadIdx.x) * 8;
  int tok = idx / EMB;
  int h = (idx % EMB) >> 6;
  float l0 = lm[(((size_t)0 * 12 + h) << 12) + tok];
  float l1 = lm[(((size_t)1 * 12 + h) << 12) + tok];
  float l2 = lm[(((size_t)2 * 12 + h) << 12) + tok];
  float l3 = lm[(((size_t)3 * 12 + h) << 12) + tok];
  float inv = 1.f / ((l0 + l1) + (l2 + l3));
  float w0 = l0 * inv, w1 = l1 * inv, w2 = l2 * inv, w3 = l3 * inv;
  bf16x8 a = *(const bf16x8*)(P0 + idx);
  bf16x8 b = *(const bf16x8*)(P1 + idx);
  bf16x8 c = *(const bf16x8*)(P2 + idx);
  bf16x8 d = *(const bf16x8*)(P3 + idx);
  bf16x8 o;
#pragma unroll
  for (int e = 0; e < 8; ++e)
    o[e] = (bf16)((w0 * (float)a[e] + w1 * (float)b[e]) +
                  (w2 * (float)c[e] + w3 * (float)d[e]));
  *(bf16x8*)(P0 + idx) = o;
}

extern "C" void kernel_launch(void* const* d_in, const int* in_sizes, int n_in,
                              void* d_out, int out_size, void* d_ws, size_t ws_size,
                              hipStream_t stream) {
  (void)in_sizes; (void)n_in; (void)out_size; (void)ws_size;
  const float* x = (const float*)d_in[0];
  const unsigned char* mask = (const unsigned char*)d_in[1];
  const float* Wq = (const float*)d_in[2];
  const float* bq = (const float*)d_in[3];
  const float* Wk = (const float*)d_in[4];
  const float* bk = (const float*)d_in[5];
  const float* Wv = (const float*)d_in[6];
  const float* bv = (const float*)d_in[7];
  const float* Wo = (const float*)d_in[8];
  const float* bo = (const float*)d_in[9];
  float* out = (float*)d_out;
  char* ws = (char*)d_ws;

  bf16* xb   = (bf16*)(ws + 0);          // 4096x768 bf16 (dead after gemm1 -> reused as P1)
  bf16* Wqb  = (bf16*)(ws + 6291456);
  bf16* Wkb  = (bf16*)(ws + 7471104);
  bf16* Wvb  = (bf16*)(ws + 8650752);
  bf16* Wob  = (bf16*)(ws + 9830400);
  bf16* Qh   = (bf16*)(ws + 11010048);   // [12][4096][64] bf16, scaled by QSC
  char* Kswz = ws + 17301504;            // [12][4096] rows of 128B, XOR-swizzled
  char* Vswz = ws + 23592960;            // [12][64] rows of 8192B, slot-perm+swizzled V^T
  bf16* Obuf = (bf16*)(ws + 29884416);   // [4096][768] bf16: attn partial 0, then merged O
  unsigned long long* tf64 = (unsigned long long*)(ws + 36175872);
  float* lmArr = (float*)(ws + 36179968);  // [4][12][4096] f32 (786 KB)
  bf16* P1 = xb;                           // partial 1 reuses xb region
  bf16* P2 = (bf16*)out;                   // partials 2,3 use d_out as scratch
  bf16* P3 = (bf16*)out + (size_t)SEQ * EMB;  // (gemm0 fully overwrites d_out after merge)

  cvt_all_kernel<<<NCVT + 1, 256, 0, stream>>>(x, Wq, Wk, Wv, Wo, xb, Wqb, Wkb, Wvb,
                                               Wob, mask, tf64);
  gemm_bt_kernel<1><<<dim3(32, 18), 256, 0, stream>>>(
      xb, Wqb, Wkb, Wvb, bq, bk, bv, nullptr, Qh, Kswz, Vswz);
  attn_kernel<<<1536, 256, 0, stream>>>(Kswz, Vswz, Qh, mask, tf64, Obuf, P1, P2, P3,
                                        lmArr);
  merge_kernel<<<1536, 256, 0, stream>>>(Obuf, P1, P2, P3, lmArr);
  gemm_bt_kernel<0><<<dim3(32, 6), 256, 0, stream>>>(
      Obuf, Wob, nullptr, nullptr, bo, nullptr, nullptr, out, nullptr, nullptr, nullptr);
}

// Round 11
// 123.028 us; speedup vs baseline: 1.1078x; 1.1078x over previous
//
#include <hip/hip_runtime.h>
#include <hip/hip_bf16.h>
#include <math.h>

typedef __bf16 bf16;
typedef __attribute__((ext_vector_type(8))) __bf16 bf16x8;
typedef __attribute__((ext_vector_type(4))) __bf16 bf16x4;
typedef __attribute__((ext_vector_type(4))) float f32x4;
typedef __attribute__((ext_vector_type(16))) float f32x16;

typedef __attribute__((address_space(1))) void* as1ptr;
typedef __attribute__((address_space(3))) void* as3ptr;

__device__ __forceinline__ void gload16(const void* g, void* lds) {
  __builtin_amdgcn_global_load_lds((as1ptr)(unsigned long long)(g),
                                   (as3ptr)(unsigned long long)(lds), 16, 0, 0);
}

#define MFMA16(a, b, c) __builtin_amdgcn_mfma_f32_16x16x32_bf16((a), (b), (c), 0, 0, 0)
#define MFMA32(a, b, c) __builtin_amdgcn_mfma_f32_32x32x16_bf16((a), (b), (c), 0, 0, 0)
#define EXP2(x) __builtin_amdgcn_exp2f(x)
#define WAITV4 asm volatile("s_waitcnt vmcnt(4)" ::: "memory")
#define WAITV2 asm volatile("s_waitcnt vmcnt(2)" ::: "memory")
#define WAITV0 asm volatile("s_waitcnt vmcnt(0)" ::: "memory")
#define BAR() __builtin_amdgcn_s_barrier()
#define PRIO1() __builtin_amdgcn_s_setprio(1)
#define PRIO0() __builtin_amdgcn_s_setprio(0)

#define SEQ 4096
#define EMB 768
// 1/sqrt(768) * log2(e): attention scores live in the log2 domain
#define QSC (0.036084391824351615f * 1.4426950408889634f)

// ------------- fused f32->bf16 converts (x, Wq, Wk, Wv, Wo) + mask tile-flag bits -------------
#define NCVT 2688  // 1536 (x) + 4*288 (weights)
__global__ __launch_bounds__(256)
void cvt_all_kernel(const float* __restrict__ x, const float* __restrict__ Wq,
                    const float* __restrict__ Wk, const float* __restrict__ Wv,
                    const float* __restrict__ Wo,
                    bf16* __restrict__ xb, bf16* __restrict__ Wqb, bf16* __restrict__ Wkb,
                    bf16* __restrict__ Wvb, bf16* __restrict__ Wob,
                    const unsigned char* __restrict__ mask,
                    unsigned long long* __restrict__ tf64) {
  int b = blockIdx.x;
  if (b == NCVT) {  // bit t of *tf64 = any(mask[64t .. 64t+63]), t = 0..63
    int t = threadIdx.x;
    if (t < 64) {
      unsigned v = 0;
      const unsigned char* mp = mask + t * 64;
      for (int i = 0; i < 64; i++) v |= mp[i];
      unsigned long long bits = __ballot(v != 0);
      if (t == 0) *tf64 = bits;
    }
    return;
  }
  const float* in;
  bf16* out;
  int base;
  if (b < 1536) {
    in = x; out = xb; base = b;
  } else {
    int r = b - 1536, seg = r / 288, off = r % 288;
    in  = (seg == 0) ? Wq  : (seg == 1) ? Wk  : (seg == 2) ? Wv  : Wo;
    out = (seg == 0) ? Wqb : (seg == 1) ? Wkb : (seg == 2) ? Wvb : Wob;
    base = off;
  }
  int i = (base * 256 + threadIdx.x) * 8;
  float4 a = *(const float4*)(in + i);
  float4 c = *(const float4*)(in + i + 4);
  bf16x8 v;
  v[0] = (bf16)a.x; v[1] = (bf16)a.y; v[2] = (bf16)a.z; v[3] = (bf16)a.w;
  v[4] = (bf16)c.x; v[5] = (bf16)c.y; v[6] = (bf16)c.z; v[7] = (bf16)c.w;
  *(bf16x8*)(out + i) = v;
}

// ---------------- QKV GEMM: out[m][n] = sum_k A[m][k]*B[n][k] + bias[n] ----------------
// 3-deep LDS pipeline, counted vmcnt(4), single raw barrier per K-step.
// Q: scaled (1/sqrt(E)*log2e) head-major; K: byte-swizzled rows;
// V: transposed V^T, slot-permuted (bits 2<->3 of within-16 key index) + swizzled.
__global__ __launch_bounds__(256)
void gemm_qkv_kernel(const bf16* __restrict__ A,
                     const bf16* __restrict__ B0, const bf16* __restrict__ B1,
                     const bf16* __restrict__ B2,
                     const float* __restrict__ bias0, const float* __restrict__ bias1,
                     const float* __restrict__ bias2,
                     bf16* __restrict__ Qh, char* __restrict__ Kswz,
                     char* __restrict__ Vswz) {
  __shared__ __attribute__((aligned(16))) char Asb[3][8192];
  __shared__ __attribute__((aligned(16))) char Bsb[3][8192];
  const int tid = threadIdx.x;
  const int wid = tid >> 6, lane = tid & 63;
  const int g = lane >> 4, c16 = lane & 15;
  const int wr = wid >> 1, wc = wid & 1;
  const int bm0 = blockIdx.x * 128;

  const int mat = blockIdx.y / 6;
  const int nb = (blockIdx.y % 6) * 128;
  const bf16* Bp = (mat == 0) ? B0 : (mat == 1 ? B1 : B2);
  const float* bias = (mat == 0) ? bias0 : (mat == 1 ? bias1 : bias2);

  const int arow = tid >> 2, acol = (tid & 3) * 16;  // tid*16 -> (row, 16B-col) in 128x32 tile

#define STAGE_G(k, b)                                                              \
  do {                                                                             \
    gload16((const char*)A + (size_t)(bm0 + arow) * (EMB * 2) + (k)*64 + acol,     \
            &Asb[b][wid * 1024]);                                                  \
    gload16((const char*)A + (size_t)(bm0 + 64 + arow) * (EMB * 2) + (k)*64 + acol,\
            &Asb[b][4096 + wid * 1024]);                                           \
    gload16((const char*)Bp + (size_t)(nb + arow) * (EMB * 2) + (k)*64 + acol,     \
            &Bsb[b][wid * 1024]);                                                  \
    gload16((const char*)Bp + (size_t)(nb + 64 + arow) * (EMB * 2) + (k)*64 + acol,\
            &Bsb[b][4096 + wid * 1024]);                                           \
  } while (0)

  f32x4 acc[4][4];
#pragma unroll
  for (int i = 0; i < 4; i++)
#pragma unroll
    for (int j = 0; j < 4; j++) acc[i][j] = f32x4{0.f, 0.f, 0.f, 0.f};

#define COMPUTE_G(cur)                                                         \
  do {                                                                         \
    bf16x8 a[4], b[4];                                                         \
    _Pragma("unroll") for (int i = 0; i < 4; i++)                              \
        a[i] = *(const bf16x8*)(&Asb[cur][(wr * 64 + i * 16 + c16) * 64 + g * 16]); \
    _Pragma("unroll") for (int j = 0; j < 4; j++)                              \
        b[j] = *(const bf16x8*)(&Bsb[cur][(wc * 64 + j * 16 + c16) * 64 + g * 16]); \
    PRIO1();                                                                   \
    _Pragma("unroll") for (int i = 0; i < 4; i++)                              \
        _Pragma("unroll") for (int j = 0; j < 4; j++)                          \
            acc[i][j] = MFMA16(a[i], b[j], acc[i][j]);                         \
    PRIO0();                                                                   \
  } while (0)

  STAGE_G(0, 0);
  STAGE_G(1, 1);
  int cur = 0;
  for (int kk = 0; kk < EMB / 32 - 1; ++kk) {
    WAITV4;
    BAR();
    if (kk < EMB / 32 - 2) {
      int stb = (cur == 0) ? 2 : cur - 1;  // (kk+2)%3
      STAGE_G(kk + 2, stb);
    }
    COMPUTE_G(cur);
    cur = (cur == 2) ? 0 : cur + 1;
  }
  WAITV0;
  BAR();
  COMPUTE_G(cur);
#undef STAGE_G
#undef COMPUTE_G

#pragma unroll
  for (int i = 0; i < 4; i++) {
#pragma unroll
    for (int j = 0; j < 4; j++) {
      int colL = nb + wc * 64 + j * 16 + c16;
      float bval = bias[colL];
#pragma unroll
      for (int r = 0; r < 4; r++) {
        int row = bm0 + wr * 64 + i * 16 + 4 * g + r;
        float val = acc[i][j][r] + bval;
        int hh = colL >> 6, d = colL & 63;
        if (mat == 0) {
          Qh[((size_t)hh * SEQ + row) * 64 + d] = (bf16)(val * QSC);
        } else if (mat == 1) {
          *(bf16*)(Kswz + ((size_t)hh * SEQ + row) * 128 +
                   ((d * 2) ^ ((row & 7) << 4))) = (bf16)val;
        } else {
          // V^T slot permutation: within each 16-key group, key w -> slot (swap bits 2,3)
          int kk2 = row & 63;
          int cc = (kk2 & 48) | (kk2 & 3) | ((kk2 & 4) << 1) | ((kk2 & 8) >> 1);
          *(bf16*)(Vswz + ((size_t)hh * 64 + d) * 8192 + (size_t)(row >> 6) * 128 +
                   ((cc * 2) ^ ((d & 7) << 4))) = (bf16)val;
        }
      }
    }
  }
}

// ---------------- Output GEMM: out = Obuf @ Wo^T + bo (f32), 64x64 tiles ----------------
// Grid (64,12) = 768 blocks = 3/CU even (was 192 = 0.75/CU). 3-buf counted vmcnt(2).
__global__ __launch_bounds__(256)
void gemm_out_kernel(const bf16* __restrict__ A, const bf16* __restrict__ B,
                     const float* __restrict__ bias, float* __restrict__ outF) {
  __shared__ __attribute__((aligned(16))) char Asb[3][4096];
  __shared__ __attribute__((aligned(16))) char Bsb[3][4096];
  const int tid = threadIdx.x;
  const int wid = tid >> 6, lane = tid & 63;
  const int g = lane >> 4, c16 = lane & 15;
  const int wr = wid >> 1, wc = wid & 1;
  const int bm0 = blockIdx.x * 64, nb = blockIdx.y * 64;
  const int arow = tid >> 2, acol = (tid & 3) * 16;  // tid*16 -> (row, col) in 64x32 tile

#define STAGE_O(k, b)                                                          \
  do {                                                                         \
    gload16((const char*)A + (size_t)(bm0 + arow) * (EMB * 2) + (k)*64 + acol, \
            &Asb[b][wid * 1024]);                                              \
    gload16((const char*)B + (size_t)(nb + arow) * (EMB * 2) + (k)*64 + acol,  \
            &Bsb[b][wid * 1024]);                                              \
  } while (0)

  f32x4 acc[2][2];
#pragma unroll
  for (int i = 0; i < 2; i++)
#pragma unroll
    for (int j = 0; j < 2; j++) acc[i][j] = f32x4{0.f, 0.f, 0.f, 0.f};

#define COMPUTE_O(cur)                                                         \
  do {                                                                         \
    bf16x8 a[2], b[2];                                                         \
    _Pragma("unroll") for (int i = 0; i < 2; i++)                              \
        a[i] = *(const bf16x8*)(&Asb[cur][(wr * 32 + i * 16 + c16) * 64 + g * 16]); \
    _Pragma("unroll") for (int j = 0; j < 2; j++)                              \
        b[j] = *(const bf16x8*)(&Bsb[cur][(wc * 32 + j * 16 + c16) * 64 + g * 16]); \
    PRIO1();                                                                   \
    _Pragma("unroll") for (int i = 0; i < 2; i++)                              \
        _Pragma("unroll") for (int j = 0; j < 2; j++)                          \
            acc[i][j] = MFMA16(a[i], b[j], acc[i][j]);                         \
    PRIO0();                                                                   \
  } while (0)

  STAGE_O(0, 0);
  STAGE_O(1, 1);
  int cur = 0;
  for (int kk = 0; kk < EMB / 32 - 1; ++kk) {
    WAITV2;
    BAR();
    if (kk < EMB / 32 - 2) {
      int stb = (cur == 0) ? 2 : cur - 1;  // (kk+2)%3
      STAGE_O(kk + 2, stb);
    }
    COMPUTE_O(cur);
    cur = (cur == 2) ? 0 : cur + 1;
  }
  WAITV0;
  BAR();
  COMPUTE_O(cur);
#undef STAGE_O
#undef COMPUTE_O

#pragma unroll
  for (int i = 0; i < 2; i++) {
#pragma unroll
    for (int j = 0; j < 2; j++) {
      int colL = nb + wc * 32 + j * 16 + c16;
      float bval = bias[colL];
#pragma unroll
      for (int r = 0; r < 4; r++) {
        int row = bm0 + wr * 32 + i * 16 + 4 * g + r;
        outF[(size_t)row * EMB + colL] = acc[i][j][r] + bval;
      }
    }
  }
}

// -------- Flash attention: 32x32 MFMA, 8 waves (4qh x 2kh), QB=128, key-split 2 --------
// MAX-FREE softmax: p = exp2(s) directly (scores are O(1) in log2 domain; masked keys
// -> exp2(-inf)=0 exactly). l computed via ones-MFMA (2 extra MFMA32 replace 15 VALU
// adds + end shuffle; l lands replicated in lacc[0]). No cross-lane ops in the loop.
__global__ __launch_bounds__(512)
void attn_kernel(const char* __restrict__ Kswz, const char* __restrict__ Vswz,
                 const bf16* __restrict__ Qh, const unsigned char* __restrict__ mask,
                 const unsigned long long* __restrict__ tf64,
                 bf16* __restrict__ P0, bf16* __restrict__ P1, float* __restrict__ lm) {
  __shared__ __attribute__((aligned(16))) char LBUF[49152];
  char* LK = LBUF;            // 3 x 8KB K tiles
  char* LV = LBUF + 24576;    // 3 x 8KB V tiles
  const int tid = threadIdx.x;
  const int wid = tid >> 6, lane = tid & 63;
  const int qh = wid >> 1, kh = wid & 1;
  const int l31 = lane & 31, hi = lane >> 5;
  // XCD swizzle: xcd = b%8 gets contiguous work range (~1.5 heads hot per XCD L2).
  const int bsw = ((blockIdx.x & 7) * 96) + (blockIdx.x >> 3);
  const int h = bsw >> 6;
  const int rem = bsw & 63;
  const int qb = rem >> 1;   // 32 query-blocks of 128
  const int ks = rem & 1;    // key-split half: keys [ks*2048, ks*2048+2048)
  const unsigned long long tfb = *tf64;
  const int NT = 32;  // 2048 / 64

  bf16x8 qa[4];  // B-frag: Q[q = qb*128+32qh+l31][d = 16c + 8hi + j]
  {
    const bf16* qp = Qh + ((size_t)h * SEQ + qb * 128 + qh * 32 + l31) * 64 + hi * 8;
    qa[0] = *(const bf16x8*)(qp);
    qa[1] = *(const bf16x8*)(qp + 16);
    qa[2] = *(const bf16x8*)(qp + 32);
    qa[3] = *(const bf16x8*)(qp + 48);
  }
  bf16x8 onesA;
#pragma unroll
  for (int e = 0; e < 8; ++e) onesA[e] = (bf16)1.0f;

  f32x16 ot0, ot1, lacc;  // O^T partial + l accumulator (all lacc rows equal)
#pragma unroll
  for (int r = 0; r < 16; r++) { ot0[r] = 0.f; ot1[r] = 0.f; lacc[r] = 0.f; }

  // staging sources: tid*16 covers the 8KB tile linearly (512 threads x 16B)
  const char* ksrc = Kswz + (size_t)h * SEQ * 128 + (size_t)ks * 2048 * 128 + tid * 16;
  const char* vsrc = Vswz + ((size_t)h * 64 + (tid >> 3)) * 8192 + ks * 4096 + (tid & 7) * 16;

#define STAGE(t, b)                                              \
  do {                                                           \
    gload16(ksrc + (size_t)(t)*8192, LK + (b)*8192 + wid * 1024);\
    gload16(vsrc + (size_t)(t)*128,  LV + (b)*8192 + wid * 1024);\
  } while (0)

  const int krow = kh * 32 + l31;          // K row this lane supplies (A-frag m)
  const int ksw = (krow & 7) << 4;
  const int vsw = (l31 & 7) << 4;          // V^T row swizzle
  const int vcb = kh * 64 + hi * 16;       // V^T slot-col byte base for this wave

#define COMPUTE(t, cur)                                                          \
  do {                                                                           \
    const char* Kb = LK + (cur)*8192;                                            \
    const char* Vb = LV + (cur)*8192;                                            \
    bf16x8 kf0 = *(const bf16x8*)(Kb + krow * 128 + ((hi * 16) ^ ksw));          \
    bf16x8 kf1 = *(const bf16x8*)(Kb + krow * 128 + ((32 + hi * 16) ^ ksw));     \
    bf16x8 kf2 = *(const bf16x8*)(Kb + krow * 128 + ((64 + hi * 16) ^ ksw));     \
    bf16x8 kf3 = *(const bf16x8*)(Kb + krow * 128 + ((96 + hi * 16) ^ ksw));     \
    f32x16 s;                                                                    \
    _Pragma("unroll") for (int r = 0; r < 16; r++) s[r] = 0.f;                   \
    PRIO1();                                                                     \
    s = MFMA32(kf0, qa[0], s);                                                   \
    s = MFMA32(kf1, qa[1], s);                                                   \
    s = MFMA32(kf2, qa[2], s);                                                   \
    s = MFMA32(kf3, qa[3], s);                                                   \
    PRIO0();                                                                     \
    if (tfb & (1ull << (ks * 32 + (t)))) {                                       \
      _Pragma("unroll") for (int r = 0; r < 16; r++) {                           \
        int key = ks * 2048 + (t)*64 + kh * 32 + (r & 3) + 8 * (r >> 2) + 4 * hi;\
        if (mask[key]) s[r] = -INFINITY;                                         \
      }                                                                          \
    }                                                                            \
    float p[16];                                                                 \
    _Pragma("unroll") for (int r = 0; r < 16; r++) p[r] = EXP2(s[r]);            \
    bf16x8 pb0, pb1;                                                             \
    _Pragma("unroll") for (int e = 0; e < 8; ++e) {                              \
      pb0[e] = (bf16)p[e];                                                       \
      pb1[e] = (bf16)p[8 + e];                                                   \
    }                                                                            \
    bf16x8 vf00 = *(const bf16x8*)(Vb + l31 * 128 + ((vcb) ^ vsw));              \
    bf16x8 vf01 = *(const bf16x8*)(Vb + l31 * 128 + ((vcb + 32) ^ vsw));         \
    bf16x8 vf10 = *(const bf16x8*)(Vb + (32 + l31) * 128 + ((vcb) ^ vsw));       \
    bf16x8 vf11 = *(const bf16x8*)(Vb + (32 + l31) * 128 + ((vcb + 32) ^ vsw));  \
    PRIO1();                                                                     \
    ot0 = MFMA32(vf00, pb0, ot0);                                                \
    ot0 = MFMA32(vf01, pb1, ot0);                                                \
    ot1 = MFMA32(vf10, pb0, ot1);                                                \
    ot1 = MFMA32(vf11, pb1, ot1);                                                \
    lacc = MFMA32(onesA, pb0, lacc);                                             \
    lacc = MFMA32(onesA, pb1, lacc);                                             \
    PRIO0();                                                                     \
  } while (0)

  STAGE(0, 0);
  STAGE(1, 1);
  int cur = 0;
  for (int t = 0; t < NT - 1; ++t) {
    WAITV2;
    BAR();
    if (t < NT - 2) {
      int stb = (cur == 0) ? 2 : cur - 1;  // (t+2)%3
      STAGE(t + 2, stb);
    }
    COMPUTE(t, cur);
    cur = (cur == 2) ? 0 : cur + 1;
  }
  WAITV0;
  BAR();
  COMPUTE(NT - 1, cur);
#undef STAGE
#undef COMPUTE

  // l[q] for this wave's 32 keys: replicated across lacc rows and both hi halves
  float l_ = lacc[0];

  // ---- merge kh=0 / kh=1 partials (plain sums -- no max terms) ----
  __syncthreads();
  float* ml = (float*)(LBUF + 32768);  // [8 waves][64 lanes]
  ml[wid * 64 + lane] = l_;
  __syncthreads();
  const int pw = wid ^ 1;
  float lt = l_ + ml[pw * 64 + lane];
  char* obase = LBUF + qh * 8192 + lane * 128;  // [4 qh][64 lanes][128B]
  const int osw = (lane & 7) << 4;
  if (kh == 1) {
#pragma unroll
    for (int u = 0; u < 4; ++u) {
      *(f32x4*)(obase + ((u * 16) ^ osw)) =
          f32x4{ot0[4 * u], ot0[4 * u + 1], ot0[4 * u + 2], ot0[4 * u + 3]};
      *(f32x4*)(obase + (((4 + u) * 16) ^ osw)) =
          f32x4{ot1[4 * u], ot1[4 * u + 1], ot1[4 * u + 2], ot1[4 * u + 3]};
    }
  }
  __syncthreads();
  if (kh == 0) {
    float inv = 1.f / lt;
    int tok = qb * 128 + qh * 32 + l31;
    bf16* Op = ks ? P1 : P0;
    bf16* op = Op + (size_t)tok * EMB + h * 64;
#pragma unroll
    for (int u = 0; u < 4; ++u) {
      f32x4 w0 = *(const f32x4*)(obase + ((u * 16) ^ osw));
      f32x4 w1 = *(const f32x4*)(obase + (((4 + u) * 16) ^ osw));
      bf16x4 o0, o1;
#pragma unroll
      for (int e = 0; e < 4; ++e) {
        o0[e] = (bf16)((ot0[4 * u + e] + w0[e]) * inv);
        o1[e] = (bf16)((ot1[4 * u + e] + w1[e]) * inv);
      }
      // d = 32f + 8u + 4hi + e
      *(bf16x4*)(op + 8 * u + 4 * hi) = o0;
      *(bf16x4*)(op + 32 + 8 * u + 4 * hi) = o1;
    }
    if (lane < 32) {  // one l per (ks, head, token), stored in slot [1]
      lm[(((size_t)ks * 12 + h) * 4096 + tok) * 2 + 1] = lt;
    }
  }
}

// -------- merge the two key-split halves: O = (l0*P0 + l1*P1)/(l0+l1), in-place into P0 --------
__global__ __launch_bounds__(256)
void merge_kernel(bf16* __restrict__ P0, const bf16* __restrict__ P1,
                  const float* __restrict__ lm) {
  int idx = (blockIdx.x * 256 + threadIdx.x) * 8;
  int tok = idx / EMB;
  int e0 = idx % EMB;
  int h = e0 >> 6;
  float l0 = lm[((size_t)h * 4096 + tok) * 2 + 1];
  float l1 = lm[(((size_t)12 + h) * 4096 + tok) * 2 + 1];
  float inv = 1.f / (l0 + l1);
  float w0 = l0 * inv;
  float w1 = l1 * inv;
  bf16x8 a = *(const bf16x8*)(P0 + idx);
  bf16x8 b = *(const bf16x8*)(P1 + idx);
  bf16x8 o;
#pragma unroll
  for (int e = 0; e < 8; ++e) o[e] = (bf16)(w0 * (float)a[e] + w1 * (float)b[e]);
  *(bf16x8*)(P0 + idx) = o;
}

extern "C" void kernel_launch(void* const* d_in, const int* in_sizes, int n_in,
                              void* d_out, int out_size, void* d_ws, size_t ws_size,
                              hipStream_t stream) {
  (void)in_sizes; (void)n_in; (void)out_size; (void)ws_size;
  const float* x = (const float*)d_in[0];
  const unsigned char* mask = (const unsigned char*)d_in[1];
  const float* Wq = (const float*)d_in[2];
  const float* bq = (const float*)d_in[3];
  const float* Wk = (const float*)d_in[4];
  const float* bk = (const float*)d_in[5];
  const float* Wv = (const float*)d_in[6];
  const float* bv = (const float*)d_in[7];
  const float* Wo = (const float*)d_in[8];
  const float* bo = (const float*)d_in[9];
  float* out = (float*)d_out;
  char* ws = (char*)d_ws;

  bf16* xb   = (bf16*)(ws + 0);          // 4096x768 bf16 (dead after gemm1 -> reused as P1)
  bf16* Wqb  = (bf16*)(ws + 6291456);
  bf16* Wkb  = (bf16*)(ws + 7471104);
  bf16* Wvb  = (bf16*)(ws + 8650752);
  bf16* Wob  = (bf16*)(ws + 9830400);
  bf16* Qh   = (bf16*)(ws + 11010048);   // [12][4096][64] bf16, scaled by QSC
  char* Kswz = ws + 17301504;            // [12][4096] rows of 128B, XOR-swizzled
  char* Vswz = ws + 23592960;            // [12][64] rows of 8192B, slot-perm+swizzled V^T
  bf16* Obuf = (bf16*)(ws + 29884416);   // [4096][768] bf16: attn partial 0, then merged O
  unsigned long long* tf64 = (unsigned long long*)(ws + 36175872);
  float* lmArr = (float*)(ws + 36179968);  // [2][12][4096][2] f32 (786 KB)
  bf16* P1 = xb;                           // partial 1 reuses xb region

  cvt_all_kernel<<<NCVT + 1, 256, 0, stream>>>(x, Wq, Wk, Wv, Wo, xb, Wqb, Wkb, Wvb,
                                               Wob, mask, tf64);
  gemm_qkv_kernel<<<dim3(32, 18), 256, 0, stream>>>(
      xb, Wqb, Wkb, Wvb, bq, bk, bv, Qh, Kswz, Vswz);
  attn_kernel<<<768, 512, 0, stream>>>(Kswz, Vswz, Qh, mask, tf64, Obuf, P1, lmArr);
  merge_kernel<<<1536, 256, 0, stream>>>(Obuf, P1, lmArr);
  gemm_out_kernel<<<dim3(64, 12), 256, 0, stream>>>(Obuf, Wob, bo, out);
}